// Round 1
// baseline (228.527 us; speedup 1.0000x reference)
//
#include <hip/hip_runtime.h>
#include <hip/hip_bf16.h>
#include <math.h>

typedef __bf16 bf16x8 __attribute__((ext_vector_type(8)));
typedef float f32x4 __attribute__((ext_vector_type(4)));
typedef unsigned short u16;

// Problem constants
constexpr int Bz = 2, T = 2048, D = 1024, H = 16;
constexpr int M = Bz * T;       // 4096 rows
constexpr int NQKV = 3 * D;     // 3072

#define GLD_LDS16(g, l) __builtin_amdgcn_global_load_lds( \
    (__attribute__((address_space(1))) void*)(g),          \
    (__attribute__((address_space(3))) void*)(l), 16, 0, 0)

// ---------------- fp32 -> bf16 conversion ----------------
__global__ void f32_to_bf16_kernel(const float* __restrict__ in,
                                   u16* __restrict__ out, int n4) {
  int i = blockIdx.x * blockDim.x + threadIdx.x;
  int stride = gridDim.x * blockDim.x;
  for (; i < n4; i += stride) {
    float4 f = ((const float4*)in)[i];
    ushort4 u;
    u.x = __builtin_bit_cast(u16, (__bf16)f.x);
    u.y = __builtin_bit_cast(u16, (__bf16)f.y);
    u.z = __builtin_bit_cast(u16, (__bf16)f.z);
    u.w = __builtin_bit_cast(u16, (__bf16)f.w);
    ((ushort4*)out)[i] = u;
  }
}

// ---------------- bf16 NT GEMM: C[M,N] = A[M,K] * B[N,K]^T ----------------
// 128x128 tile, BK=64, 256 threads (4 waves, 2x2, each 64x64 out).
// LDS linear [128][64] bf16 with XOR chunk swizzle: stored chunk cs holds
// logical chunk cs ^ (row&7). global_load_lds dest is linear; source is
// inverse-swizzled (rule #21: both-sides-or-neither).
template <bool FP32OUT>
__global__ __launch_bounds__(256, 2)
void gemm_bt(const u16* __restrict__ A, const u16* __restrict__ Bm,
             u16* __restrict__ outb, float* __restrict__ outf,
             const float* __restrict__ bias, int K, int ldc) {
  __shared__ __align__(16) u16 sA[128 * 64];
  __shared__ __align__(16) u16 sB[128 * 64];
  const int tid = threadIdx.x;
  const int lane = tid & 63;
  const int wid = tid >> 6;
  const int wr = wid >> 1, wc = wid & 1;
  const int row0 = blockIdx.y * 128;
  const int col0 = blockIdx.x * 128;

  f32x4 acc[4][4];
#pragma unroll
  for (int m = 0; m < 4; ++m)
#pragma unroll
    for (int n = 0; n < 4; ++n) acc[m][n] = (f32x4){0.f, 0.f, 0.f, 0.f};

  const int nk = K >> 6;
  for (int kt = 0; kt < nk; ++kt) {
    const int k0 = kt << 6;
    // stage A and B tiles: 16KB each; per thread 4 x 16B each
#pragma unroll
    for (int i = 0; i < 4; ++i) {
      int off = i * 4096 + tid * 16;       // linear byte offset in tile
      int r = off >> 7;                    // row (128B rows)
      int cs = (off >> 4) & 7;             // stored chunk
      int c = cs ^ (r & 7);                // logical (source) chunk
      const u16* ga = A + (size_t)(row0 + r) * K + k0 + c * 8;
      const u16* gb = Bm + (size_t)(col0 + r) * K + k0 + c * 8;
      u16* la = sA + (i * 4096 + (tid & ~63) * 16) / 2;  // wave-uniform base
      u16* lb = sB + (i * 4096 + (tid & ~63) * 16) / 2;
      GLD_LDS16(ga, la);
      GLD_LDS16(gb, lb);
    }
    __syncthreads();
#pragma unroll
    for (int kk = 0; kk < 2; ++kk) {
      bf16x8 af[4], bfv[4];
#pragma unroll
      for (int m = 0; m < 4; ++m) {
        int r = wr * 64 + m * 16 + (lane & 15);
        int cs = (kk * 4 + (lane >> 4)) ^ (r & 7);
        af[m] = *(const bf16x8*)(sA + r * 64 + cs * 8);
      }
#pragma unroll
      for (int n = 0; n < 4; ++n) {
        int r = wc * 64 + n * 16 + (lane & 15);
        int cs = (kk * 4 + (lane >> 4)) ^ (r & 7);
        bfv[n] = *(const bf16x8*)(sB + r * 64 + cs * 8);
      }
#pragma unroll
      for (int m = 0; m < 4; ++m)
#pragma unroll
        for (int n = 0; n < 4; ++n)
          acc[m][n] = __builtin_amdgcn_mfma_f32_16x16x32_bf16(
              af[m], bfv[n], acc[m][n], 0, 0, 0);
    }
    __syncthreads();
  }

  // epilogue: C/D layout col=lane&15, row=(lane>>4)*4+j
  const int orow0 = row0 + wr * 64;
  const int ocol0 = col0 + wc * 64;
#pragma unroll
  for (int m = 0; m < 4; ++m)
#pragma unroll
    for (int n = 0; n < 4; ++n)
#pragma unroll
      for (int j = 0; j < 4; ++j) {
        int rr = orow0 + m * 16 + (lane >> 4) * 4 + j;
        int cc = ocol0 + n * 16 + (lane & 15);
        if (FP32OUT)
          outf[(size_t)rr * ldc + cc] = acc[m][n][j] + bias[cc];
        else
          outb[(size_t)rr * ldc + cc] =
              __builtin_bit_cast(u16, (__bf16)acc[m][n][j]);
      }
}

// ---------------- causal flash attention ----------------
// qkv: [M][3072] bf16 (q|k|v each D=1024, head h at h*64).
// Block: 256 thr = 4 waves; block handles 64 Q rows of one (b,h).
// Wave w owns rows q0+w*16 .. +15. K-tile = 64 keys.
__global__ __launch_bounds__(256, 2)
void flash_kernel(const u16* __restrict__ qkv, u16* __restrict__ attn_out) {
  __shared__ __align__(16) u16 sK[64 * 64];      // swizzled [keypos][64]
  __shared__ __align__(16) u16 sVt[64 * 72];     // [d][keypos] padded
  __shared__ __align__(16) u16 sP[4][16][72];    // per-wave P, padded

  const int tid = threadIdx.x;
  const int lane = tid & 63;
  const int w = tid >> 6;
  const int bh = blockIdx.y;           // 0..31
  const int b = bh >> 4, h = bh & 15;
  const int qt = blockIdx.x;           // 0..31
  const int q0 = qt * 64;

  const size_t base = (size_t)b * T * 3072;
  const u16* qp = qkv + base + 0 * 1024 + h * 64;
  const u16* kp = qkv + base + 1 * 1024 + h * 64;
  const u16* vp = qkv + base + 2 * 1024 + h * 64;

  // Q fragments straight from global (A-frag layout: row=lane&15, k=(lane>>4)*8+j)
  const int qrow_frag = q0 + w * 16 + (lane & 15);
  bf16x8 qf[2];
#pragma unroll
  for (int kk = 0; kk < 2; ++kk)
    qf[kk] = *(const bf16x8*)(qp + (size_t)qrow_frag * 3072 + kk * 32 +
                              (lane >> 4) * 8);

  f32x4 o_acc[4];
#pragma unroll
  for (int n = 0; n < 4; ++n) o_acc[n] = (f32x4){0.f, 0.f, 0.f, 0.f};
  float m_run[4], l_run[4];
#pragma unroll
  for (int j = 0; j < 4; ++j) { m_run[j] = -INFINITY; l_run[j] = 0.f; }

  for (int kt = 0; kt <= qt; ++kt) {
    const int k0 = kt * 64;
    // stage K tile (8KB) via global_load_lds, swizzled source
#pragma unroll
    for (int i = 0; i < 2; ++i) {
      int off = i * 4096 + tid * 16;
      int r = off >> 7;
      int cs = (off >> 4) & 7;
      int c = cs ^ (r & 7);
      const u16* g = kp + (size_t)(k0 + r) * 3072 + c * 8;
      u16* l = sK + (i * 4096 + (tid & ~63) * 16) / 2;
      GLD_LDS16(g, l);
    }
    // stage V transposed: [d][keypos], pad rows to 72
#pragma unroll
    for (int i = 0; i < 2; ++i) {
      int idx = i * 256 + tid;          // 0..511 chunks of 8
      int r = idx >> 3;                 // keypos
      int c = idx & 7;                  // chunk of 8 d
      const u16* g = vp + (size_t)(k0 + r) * 3072 + c * 8;
      ushort4 v0 = ((const ushort4*)g)[0];
      ushort4 v1 = ((const ushort4*)g)[1];
      sVt[(c * 8 + 0) * 72 + r] = v0.x;
      sVt[(c * 8 + 1) * 72 + r] = v0.y;
      sVt[(c * 8 + 2) * 72 + r] = v0.z;
      sVt[(c * 8 + 3) * 72 + r] = v0.w;
      sVt[(c * 8 + 4) * 72 + r] = v1.x;
      sVt[(c * 8 + 5) * 72 + r] = v1.y;
      sVt[(c * 8 + 6) * 72 + r] = v1.z;
      sVt[(c * 8 + 7) * 72 + r] = v1.w;
    }
    __syncthreads();

    // S = Q @ K^T  (16x64 per wave)
    f32x4 s_acc[4];
#pragma unroll
    for (int n = 0; n < 4; ++n) s_acc[n] = (f32x4){0.f, 0.f, 0.f, 0.f};
#pragma unroll
    for (int kk = 0; kk < 2; ++kk) {
#pragma unroll
      for (int n = 0; n < 4; ++n) {
        int r = n * 16 + (lane & 15);                 // key col
        int cs = (kk * 4 + (lane >> 4)) ^ (r & 7);
        bf16x8 kf = *(const bf16x8*)(sK + r * 64 + cs * 8);
        s_acc[n] = __builtin_amdgcn_mfma_f32_16x16x32_bf16(qf[kk], kf,
                                                           s_acc[n], 0, 0, 0);
      }
    }

    // scale + causal mask + online softmax (wave-parallel)
    const bool diag = (kt == qt);
    float alpha[4];
#pragma unroll
    for (int j = 0; j < 4; ++j) {
      const int qr = q0 + w * 16 + (lane >> 4) * 4 + j;
      float mx = -INFINITY;
#pragma unroll
      for (int n = 0; n < 4; ++n) {
        float s = s_acc[n][j] * 0.125f;
        if (diag) {
          int kc = k0 + n * 16 + (lane & 15);
          if (kc > qr) s = -INFINITY;
        }
        s_acc[n][j] = s;
        mx = fmaxf(mx, s);
      }
#pragma unroll
      for (int d2 = 1; d2 < 16; d2 <<= 1)
        mx = fmaxf(mx, __shfl_xor(mx, d2, 64));
      float m_new = fmaxf(m_run[j], mx);
      alpha[j] = __expf(m_run[j] - m_new);
      float sum = 0.f;
#pragma unroll
      for (int n = 0; n < 4; ++n) {
        float p = __expf(s_acc[n][j] - m_new);
        s_acc[n][j] = p;
        sum += p;
      }
#pragma unroll
      for (int d2 = 1; d2 < 16; d2 <<= 1) sum += __shfl_xor(sum, d2, 64);
      m_run[j] = m_new;
      l_run[j] = l_run[j] * alpha[j] + sum;
    }

    // P (C-layout) -> LDS (A-layout source), per-wave private
#pragma unroll
    for (int n = 0; n < 4; ++n)
#pragma unroll
      for (int j = 0; j < 4; ++j)
        sP[w][(lane >> 4) * 4 + j][n * 16 + (lane & 15)] =
            __builtin_bit_cast(u16, (__bf16)s_acc[n][j]);

    // rescale O
#pragma unroll
    for (int n = 0; n < 4; ++n)
#pragma unroll
      for (int j = 0; j < 4; ++j) o_acc[n][j] *= alpha[j];

    // O += P @ V
#pragma unroll
    for (int kk = 0; kk < 2; ++kk) {
      bf16x8 pf =
          *(const bf16x8*)(&sP[w][lane & 15][kk * 32 + (lane >> 4) * 8]);
#pragma unroll
      for (int n = 0; n < 4; ++n) {
        const u16* vptr =
            sVt + (n * 16 + (lane & 15)) * 72 + kk * 32 + (lane >> 4) * 8;
        bf16x8 vf = *(const bf16x8*)vptr;
        o_acc[n] = __builtin_amdgcn_mfma_f32_16x16x32_bf16(pf, vf, o_acc[n],
                                                           0, 0, 0);
      }
    }
    __syncthreads();   // before restaging sK/sVt
  }

  // normalize + store bf16 [M][1024]
#pragma unroll
  for (int n = 0; n < 4; ++n)
#pragma unroll
    for (int j = 0; j < 4; ++j) {
      int r = q0 + w * 16 + (lane >> 4) * 4 + j;
      int cc = h * 64 + n * 16 + (lane & 15);
      attn_out[((size_t)b * T + r) * 1024 + cc] =
          __builtin_bit_cast(u16, (__bf16)(o_acc[n][j] / l_run[j]));
    }
}

// ---------------- launch ----------------
extern "C" void kernel_launch(void* const* d_in, const int* in_sizes, int n_in,
                              void* d_out, int out_size, void* d_ws,
                              size_t ws_size, hipStream_t stream) {
  (void)in_sizes; (void)n_in; (void)out_size; (void)ws_size;
  const float* x = (const float*)d_in[0];
  const float* Wqkv = (const float*)d_in[1];
  const float* Wout = (const float*)d_in[2];
  const float* bout = (const float*)d_in[3];
  float* out = (float*)d_out;

  char* ws = (char*)d_ws;
  u16* x_bf = (u16*)(ws + 0);                 //  8388608 B
  u16* wqkv_bf = (u16*)(ws + 8388608);        //  6291456 B
  u16* wout_bf = (u16*)(ws + 14680064);       //  2097152 B
  u16* qkvb = (u16*)(ws + 16777216);          // 25165824 B
  u16* aout = (u16*)(ws + 41943040);          //  8388608 B (end 50331648)

  f32_to_bf16_kernel<<<2048, 256, 0, stream>>>(x, x_bf, M * D / 4);
  f32_to_bf16_kernel<<<2048, 256, 0, stream>>>(Wqkv, wqkv_bf, NQKV * D / 4);
  f32_to_bf16_kernel<<<1024, 256, 0, stream>>>(Wout, wout_bf, D * D / 4);

  gemm_bt<false><<<dim3(NQKV / 128, M / 128), 256, 0, stream>>>(
      x_bf, wqkv_bf, qkvb, nullptr, nullptr, D, NQKV);

  flash_kernel<<<dim3(T / 64, Bz * H), 256, 0, stream>>>(qkvb, aout);

  gemm_bt<true><<<dim3(D / 128, M / 128), 256, 0, stream>>>(
      aout, wout_bf, nullptr, out, bout, D, D);
}

// Round 2
// 146.955 us; speedup vs baseline: 1.5551x; 1.5551x over previous
//
#include <hip/hip_runtime.h>
#include <hip/hip_bf16.h>
#include <math.h>

typedef __bf16 bf16x8 __attribute__((ext_vector_type(8)));
typedef float f32x4 __attribute__((ext_vector_type(4)));
typedef unsigned short u16;
typedef unsigned int u32;

// Problem constants
constexpr int Bz = 2, T = 2048, D = 1024, H = 16;
constexpr int M = Bz * T;       // 4096 rows
constexpr int NQKV = 3 * D;     // 3072

#define GLD_LDS16(g, l) __builtin_amdgcn_global_load_lds( \
    (__attribute__((address_space(1))) void*)(g),          \
    (__attribute__((address_space(3))) void*)(l), 16, 0, 0)

// ---------------- fp32 -> bf16 conversion ----------------
__global__ void f32_to_bf16_kernel(const float* __restrict__ in,
                                   u16* __restrict__ out, int n4) {
  int i = blockIdx.x * blockDim.x + threadIdx.x;
  int stride = gridDim.x * blockDim.x;
  for (; i < n4; i += stride) {
    float4 f = ((const float4*)in)[i];
    ushort4 u;
    u.x = __builtin_bit_cast(u16, (__bf16)f.x);
    u.y = __builtin_bit_cast(u16, (__bf16)f.y);
    u.z = __builtin_bit_cast(u16, (__bf16)f.z);
    u.w = __builtin_bit_cast(u16, (__bf16)f.w);
    ((ushort4*)out)[i] = u;
  }
}

// ---------------- bf16 NT GEMM: C[M,N] = A[M,K] * B[N,K]^T ----------------
// 128x128 tile, BK=64, 256 threads (4 waves, 2x2, each 64x64 out).
// XOR chunk swizzle on LDS (rule #21: linear dest + inverse-swizzled source).
// T1: XCD-aware block swizzle (grids are multiples of 8).
template <bool FP32OUT>
__global__ __launch_bounds__(256, 2)
void gemm_bt(const u16* __restrict__ A, const u16* __restrict__ Bm,
             u16* __restrict__ outb, float* __restrict__ outf,
             const float* __restrict__ bias, int K, int ldc) {
  __shared__ __align__(16) u16 sA[128 * 64];
  __shared__ __align__(16) u16 sB[128 * 64];
  const int tid = threadIdx.x;
  const int lane = tid & 63;
  const int wid = tid >> 6;
  const int wr = wid >> 1, wc = wid & 1;

  // XCD swizzle (bijective; grids here are %8 == 0)
  const int nwg = gridDim.x * gridDim.y;
  const int flat = blockIdx.y * gridDim.x + blockIdx.x;
  const int cpx = nwg >> 3;
  const int swz = (flat & 7) * cpx + (flat >> 3);
  const int bx = swz % gridDim.x;
  const int by = swz / gridDim.x;

  const int row0 = by * 128;
  const int col0 = bx * 128;

  f32x4 acc[4][4];
#pragma unroll
  for (int m = 0; m < 4; ++m)
#pragma unroll
    for (int n = 0; n < 4; ++n) acc[m][n] = (f32x4){0.f, 0.f, 0.f, 0.f};

  const int nk = K >> 6;
  for (int kt = 0; kt < nk; ++kt) {
    const int k0 = kt << 6;
#pragma unroll
    for (int i = 0; i < 4; ++i) {
      int off = i * 4096 + tid * 16;       // linear byte offset in tile
      int r = off >> 7;                    // row (128B rows)
      int cs = (off >> 4) & 7;             // stored chunk
      int c = cs ^ (r & 7);                // logical (source) chunk
      const u16* ga = A + (size_t)(row0 + r) * K + k0 + c * 8;
      const u16* gb = Bm + (size_t)(col0 + r) * K + k0 + c * 8;
      u16* la = sA + (i * 4096 + (tid & ~63) * 16) / 2;  // wave-uniform base
      u16* lb = sB + (i * 4096 + (tid & ~63) * 16) / 2;
      GLD_LDS16(ga, la);
      GLD_LDS16(gb, lb);
    }
    __syncthreads();
#pragma unroll
    for (int kk = 0; kk < 2; ++kk) {
      bf16x8 af[4], bfv[4];
#pragma unroll
      for (int m = 0; m < 4; ++m) {
        int r = wr * 64 + m * 16 + (lane & 15);
        int cs = (kk * 4 + (lane >> 4)) ^ (r & 7);
        af[m] = *(const bf16x8*)(sA + r * 64 + cs * 8);
      }
#pragma unroll
      for (int n = 0; n < 4; ++n) {
        int r = wc * 64 + n * 16 + (lane & 15);
        int cs = (kk * 4 + (lane >> 4)) ^ (r & 7);
        bfv[n] = *(const bf16x8*)(sB + r * 64 + cs * 8);
      }
#pragma unroll
      for (int m = 0; m < 4; ++m)
#pragma unroll
        for (int n = 0; n < 4; ++n)
          acc[m][n] = __builtin_amdgcn_mfma_f32_16x16x32_bf16(
              af[m], bfv[n], acc[m][n], 0, 0, 0);
    }
    __syncthreads();
  }

  const int orow0 = row0 + wr * 64;
  const int ocol0 = col0 + wc * 64;
#pragma unroll
  for (int m = 0; m < 4; ++m)
#pragma unroll
    for (int n = 0; n < 4; ++n)
#pragma unroll
      for (int j = 0; j < 4; ++j) {
        int rr = orow0 + m * 16 + (lane >> 4) * 4 + j;
        int cc = ocol0 + n * 16 + (lane & 15);
        if (FP32OUT)
          outf[(size_t)rr * ldc + cc] = acc[m][n][j] + bias[cc];
        else
          outb[(size_t)rr * ldc + cc] =
              __builtin_bit_cast(u16, (__bf16)acc[m][n][j]);
      }
}

// ---------------- causal flash attention (swapped QK^T) ----------------
// Block: 256 thr = 4 waves; block handles 128 Q rows of one (b,h).
// Wave w owns rows q0+w*32 .. +31 (two 16-row sets g=0,1). K-tile = 64 keys.
// Swapped: S^T = mfma(K, Q) -> lane holds 16 scores of ONE q-row (lane&15);
// row reductions are in-lane + 2 shfl_xor. Double-buffered K/V, 1 barrier/tile.
__global__ __launch_bounds__(256, 2)
void flash_kernel(const u16* __restrict__ qkv, u16* __restrict__ attn_out) {
  __shared__ __align__(16) u16 sK[2][64 * 64];       // swizzled [keypos][64]
  __shared__ __align__(16) u16 sVt[2][64 * 72];      // [d][keypos] pad 72
  __shared__ __align__(16) u16 sP[4][2][16][72];     // [wave][g][qrow][kpos]

  const int tid = threadIdx.x;
  const int lane = tid & 63;
  const int l15 = lane & 15;
  const int hi = lane >> 4;
  const int w = tid >> 6;
  const int bh = blockIdx.y;           // 0..31
  const int b = bh >> 4, h = bh & 15;
  const int qt = (gridDim.x - 1) - blockIdx.x;   // heavy blocks first
  const int q0 = qt * 128;
  const int nt = 2 * qt + 2;

  const size_t base = (size_t)b * T * 3072;
  const u16* qp = qkv + base + 0 * 1024 + h * 64;
  const u16* kp = qkv + base + 1 * 1024 + h * 64;
  const u16* vp = qkv + base + 2 * 1024 + h * 64;

  // Q fragments (B-operand layout: col=lane&15=qrow, k=(lane>>4)*8+j)
  bf16x8 qf[2][2];
#pragma unroll
  for (int g = 0; g < 2; ++g)
#pragma unroll
    for (int kk = 0; kk < 2; ++kk)
      qf[g][kk] = *(const bf16x8*)(qp +
          (size_t)(q0 + w * 32 + g * 16 + l15) * 3072 + kk * 32 + hi * 8);

  f32x4 o_acc[2][4];
#pragma unroll
  for (int g = 0; g < 2; ++g)
#pragma unroll
    for (int n = 0; n < 4; ++n) o_acc[g][n] = (f32x4){0.f, 0.f, 0.f, 0.f};
  float m_run[2] = {-INFINITY, -INFINITY};
  float l_run[2] = {0.f, 0.f};

  ushort4 vr[2][2];

  // --- staging helpers ---
  auto stageK = [&](u16* dst, int kt) {
#pragma unroll
    for (int i = 0; i < 2; ++i) {
      int off = i * 4096 + tid * 16;
      int r = off >> 7;
      int cs = (off >> 4) & 7;
      int c = cs ^ (r & 7);
      GLD_LDS16(kp + (size_t)(kt * 64 + r) * 3072 + c * 8,
                dst + (i * 4096 + (tid & ~63) * 16) / 2);
    }
  };
  auto loadV = [&](int kt) {
#pragma unroll
    for (int i = 0; i < 2; ++i) {
      const u16* gsrc = vp + (size_t)(kt * 64 + lane) * 3072 + (i * 4 + w) * 8;
      vr[i][0] = ((const ushort4*)gsrc)[0];
      vr[i][1] = ((const ushort4*)gsrc)[1];
    }
  };
  auto writeV = [&](u16* dst) {   // conflict-free: bank = 4k + lane/2
#pragma unroll
    for (int i = 0; i < 2; ++i) {
      int c = i * 4 + w;
      dst[(c * 8 + 0) * 72 + lane] = vr[i][0].x;
      dst[(c * 8 + 1) * 72 + lane] = vr[i][0].y;
      dst[(c * 8 + 2) * 72 + lane] = vr[i][0].z;
      dst[(c * 8 + 3) * 72 + lane] = vr[i][0].w;
      dst[(c * 8 + 4) * 72 + lane] = vr[i][1].x;
      dst[(c * 8 + 5) * 72 + lane] = vr[i][1].y;
      dst[(c * 8 + 6) * 72 + lane] = vr[i][1].z;
      dst[(c * 8 + 7) * 72 + lane] = vr[i][1].w;
    }
  };

  // prologue: stage tile 0
  stageK(sK[0], 0);
  loadV(0);
  writeV(sVt[0]);
  __syncthreads();

  for (int kt = 0; kt < nt; ++kt) {
    const int cur = kt & 1;
    const int k0 = kt * 64;
    if (kt + 1 < nt) {        // issue next-tile loads before compute
      stageK(sK[cur ^ 1], kt + 1);
      loadV(kt + 1);
    }

    // K fragments (A-operand: row=lane&15=kpos-within-tile, k=(lane>>4)*8+j)
    bf16x8 kf[2][4];
#pragma unroll
    for (int kk = 0; kk < 2; ++kk)
#pragma unroll
      for (int n = 0; n < 4; ++n) {
        int rk = n * 16 + l15;
        int cs = (kk * 4 + hi) ^ (rk & 7);
        kf[kk][n] = *(const bf16x8*)(&sK[cur][rk * 64 + cs * 8]);
      }

    // S^T = K @ Q^T : lane holds S[kpos = n*16+hi*4+r][qrow = l15]
    f32x4 sc[2][4];
#pragma unroll
    for (int g = 0; g < 2; ++g)
#pragma unroll
      for (int n = 0; n < 4; ++n) sc[g][n] = (f32x4){0.f, 0.f, 0.f, 0.f};
#pragma unroll
    for (int g = 0; g < 2; ++g)
#pragma unroll
      for (int kk = 0; kk < 2; ++kk)
#pragma unroll
        for (int n = 0; n < 4; ++n)
          sc[g][n] = __builtin_amdgcn_mfma_f32_16x16x32_bf16(
              kf[kk][n], qf[g][kk], sc[g][n], 0, 0, 0);

    // online softmax, in-lane over 16 scores + 2 shfl_xor
    const bool needm = (kt >= nt - 2);
    float alpha[2];
#pragma unroll
    for (int g = 0; g < 2; ++g) {
      const int qrow = q0 + w * 32 + g * 16 + l15;
      float mx = -INFINITY;
#pragma unroll
      for (int n = 0; n < 4; ++n)
#pragma unroll
        for (int r = 0; r < 4; ++r) {
          float sv = sc[g][n][r] * 0.125f;
          if (needm) {
            int kpos = k0 + n * 16 + hi * 4 + r;
            if (kpos > qrow) sv = -INFINITY;
          }
          sc[g][n][r] = sv;
          mx = fmaxf(mx, sv);
        }
      mx = fmaxf(mx, __shfl_xor(mx, 16, 64));
      mx = fmaxf(mx, __shfl_xor(mx, 32, 64));
      float mn = fmaxf(m_run[g], mx);
      float al = __expf(m_run[g] - mn);
      m_run[g] = mn;
      float sum = 0.f;
#pragma unroll
      for (int n = 0; n < 4; ++n) {
        float p0 = __expf(sc[g][n][0] - mn);
        float p1 = __expf(sc[g][n][1] - mn);
        float p2 = __expf(sc[g][n][2] - mn);
        float p3 = __expf(sc[g][n][3] - mn);
        sum += (p0 + p1) + (p2 + p3);
        u32 w01 = ((u32)__builtin_bit_cast(u16, (__bf16)p1) << 16) |
                  __builtin_bit_cast(u16, (__bf16)p0);
        u32 w23 = ((u32)__builtin_bit_cast(u16, (__bf16)p3) << 16) |
                  __builtin_bit_cast(u16, (__bf16)p2);
        *(u32*)(&sP[w][g][l15][n * 16 + hi * 4 + 0]) = w01;
        *(u32*)(&sP[w][g][l15][n * 16 + hi * 4 + 2]) = w23;
      }
      sum += __shfl_xor(sum, 16, 64);
      sum += __shfl_xor(sum, 32, 64);
      l_run[g] = l_run[g] * al + sum;
      alpha[g] = al;
    }

    // V fragments (B-operand: col=l15=d-within-tile, k=kpos)
    bf16x8 vf[2][4];
#pragma unroll
    for (int ks = 0; ks < 2; ++ks)
#pragma unroll
      for (int n = 0; n < 4; ++n)
        vf[ks][n] = *(const bf16x8*)(
            &sVt[cur][(n * 16 + l15) * 72 + ks * 32 + hi * 8]);

    // O rescale + O += P @ V   (O rows = hi*4+j, alpha broadcast via shfl)
#pragma unroll
    for (int g = 0; g < 2; ++g) {
      float ab[4];
#pragma unroll
      for (int j = 0; j < 4; ++j) ab[j] = __shfl(alpha[g], hi * 4 + j, 64);
#pragma unroll
      for (int n = 0; n < 4; ++n)
#pragma unroll
        for (int j = 0; j < 4; ++j) o_acc[g][n][j] *= ab[j];
#pragma unroll
      for (int ks = 0; ks < 2; ++ks) {
        bf16x8 pf = *(const bf16x8*)(&sP[w][g][l15][ks * 32 + hi * 8]);
#pragma unroll
        for (int n = 0; n < 4; ++n)
          o_acc[g][n] = __builtin_amdgcn_mfma_f32_16x16x32_bf16(
              pf, vf[ks][n], o_acc[g][n], 0, 0, 0);
      }
    }

    if (kt + 1 < nt) writeV(sVt[cur ^ 1]);   // after compute: latency hidden
    __syncthreads();
  }

  // normalize + store bf16 [M][1024]
#pragma unroll
  for (int g = 0; g < 2; ++g)
#pragma unroll
    for (int j = 0; j < 4; ++j) {
      float lj = __shfl(l_run[g], hi * 4 + j, 64);
      float inv = 1.f / lj;
      int row = q0 + w * 32 + g * 16 + hi * 4 + j;
#pragma unroll
      for (int n = 0; n < 4; ++n) {
        int cc = h * 64 + n * 16 + l15;
        attn_out[((size_t)b * T + row) * 1024 + cc] =
            __builtin_bit_cast(u16, (__bf16)(o_acc[g][n][j] * inv));
      }
    }
}

// ---------------- launch ----------------
extern "C" void kernel_launch(void* const* d_in, const int* in_sizes, int n_in,
                              void* d_out, int out_size, void* d_ws,
                              size_t ws_size, hipStream_t stream) {
  (void)in_sizes; (void)n_in; (void)out_size; (void)ws_size;
  const float* x = (const float*)d_in[0];
  const float* Wqkv = (const float*)d_in[1];
  const float* Wout = (const float*)d_in[2];
  const float* bout = (const float*)d_in[3];
  float* out = (float*)d_out;

  char* ws = (char*)d_ws;
  u16* x_bf = (u16*)(ws + 0);                 //  8388608 B
  u16* wqkv_bf = (u16*)(ws + 8388608);        //  6291456 B
  u16* wout_bf = (u16*)(ws + 14680064);       //  2097152 B
  u16* qkvb = (u16*)(ws + 16777216);          // 25165824 B
  u16* aout = (u16*)(ws + 41943040);          //  8388608 B (end 50331648)

  f32_to_bf16_kernel<<<2048, 256, 0, stream>>>(x, x_bf, M * D / 4);
  f32_to_bf16_kernel<<<2048, 256, 0, stream>>>(Wqkv, wqkv_bf, NQKV * D / 4);
  f32_to_bf16_kernel<<<1024, 256, 0, stream>>>(Wout, wout_bf, D * D / 4);

  gemm_bt<false><<<dim3(NQKV / 128, M / 128), 256, 0, stream>>>(
      x_bf, wqkv_bf, qkvb, nullptr, nullptr, D, NQKV);

  flash_kernel<<<dim3(T / 128, Bz * H), 256, 0, stream>>>(qkvb, aout);

  gemm_bt<true><<<dim3(D / 128, M / 128), 256, 0, stream>>>(
      aout, wout_bf, nullptr, out, bout, D, D);
}

// Round 4
// 129.341 us; speedup vs baseline: 1.7669x; 1.1362x over previous
//
#include <hip/hip_runtime.h>
#include <hip/hip_bf16.h>
#include <math.h>

typedef __bf16 bf16x8 __attribute__((ext_vector_type(8)));
typedef float f32x4 __attribute__((ext_vector_type(4)));
typedef unsigned short u16;
typedef unsigned int u32;

#define EXP2F(x) __builtin_amdgcn_exp2f(x)

// Problem constants
constexpr int Bz = 2, T = 2048, D = 1024, H = 16;
constexpr int M = Bz * T;       // 4096 rows
constexpr int NQKV = 3 * D;     // 3072

#define GLD_LDS16(g, l) __builtin_amdgcn_global_load_lds( \
    (__attribute__((address_space(1))) void*)(g),          \
    (__attribute__((address_space(3))) void*)(l), 16, 0, 0)

// ---------------- fp32 -> bf16 conversion ----------------
__global__ void f32_to_bf16_kernel(const float* __restrict__ in,
                                   u16* __restrict__ out, int n4) {
  int i = blockIdx.x * blockDim.x + threadIdx.x;
  int stride = gridDim.x * blockDim.x;
  for (; i < n4; i += stride) {
    float4 f = ((const float4*)in)[i];
    ushort4 u;
    u.x = __builtin_bit_cast(u16, (__bf16)f.x);
    u.y = __builtin_bit_cast(u16, (__bf16)f.y);
    u.z = __builtin_bit_cast(u16, (__bf16)f.z);
    u.w = __builtin_bit_cast(u16, (__bf16)f.w);
    ((ushort4*)out)[i] = u;
  }
}

// ---------------- bf16 NT GEMM: C[M,N] = A[M,K] * B[N,K]^T ----------------
template <bool FP32OUT>
__global__ __launch_bounds__(256, 2)
void gemm_bt(const u16* __restrict__ A, const u16* __restrict__ Bm,
             u16* __restrict__ outb, float* __restrict__ outf,
             const float* __restrict__ bias, int K, int ldc) {
  __shared__ __align__(16) u16 sA[128 * 64];
  __shared__ __align__(16) u16 sB[128 * 64];
  const int tid = threadIdx.x;
  const int lane = tid & 63;
  const int wid = tid >> 6;
  const int wr = wid >> 1, wc = wid & 1;

  // XCD swizzle (bijective; grids here are %8 == 0)
  const int nwg = gridDim.x * gridDim.y;
  const int flat = blockIdx.y * gridDim.x + blockIdx.x;
  const int cpx = nwg >> 3;
  const int swz = (flat & 7) * cpx + (flat >> 3);
  const int bx = swz % gridDim.x;
  const int by = swz / gridDim.x;

  const int row0 = by * 128;
  const int col0 = bx * 128;

  f32x4 acc[4][4];
#pragma unroll
  for (int m = 0; m < 4; ++m)
#pragma unroll
    for (int n = 0; n < 4; ++n) acc[m][n] = (f32x4){0.f, 0.f, 0.f, 0.f};

  const int nk = K >> 6;
  for (int kt = 0; kt < nk; ++kt) {
    const int k0 = kt << 6;
#pragma unroll
    for (int i = 0; i < 4; ++i) {
      int off = i * 4096 + tid * 16;       // linear byte offset in tile
      int r = off >> 7;                    // row (128B rows)
      int cs = (off >> 4) & 7;             // stored chunk
      int c = cs ^ (r & 7);                // logical (source) chunk
      const u16* ga = A + (size_t)(row0 + r) * K + k0 + c * 8;
      const u16* gb = Bm + (size_t)(col0 + r) * K + k0 + c * 8;
      u16* la = sA + (i * 4096 + (tid & ~63) * 16) / 2;  // wave-uniform base
      u16* lb = sB + (i * 4096 + (tid & ~63) * 16) / 2;
      GLD_LDS16(ga, la);
      GLD_LDS16(gb, lb);
    }
    __syncthreads();
#pragma unroll
    for (int kk = 0; kk < 2; ++kk) {
      bf16x8 af[4], bfv[4];
#pragma unroll
      for (int m = 0; m < 4; ++m) {
        int r = wr * 64 + m * 16 + (lane & 15);
        int cs = (kk * 4 + (lane >> 4)) ^ (r & 7);
        af[m] = *(const bf16x8*)(sA + r * 64 + cs * 8);
      }
#pragma unroll
      for (int n = 0; n < 4; ++n) {
        int r = wc * 64 + n * 16 + (lane & 15);
        int cs = (kk * 4 + (lane >> 4)) ^ (r & 7);
        bfv[n] = *(const bf16x8*)(sB + r * 64 + cs * 8);
      }
#pragma unroll
      for (int m = 0; m < 4; ++m)
#pragma unroll
        for (int n = 0; n < 4; ++n)
          acc[m][n] = __builtin_amdgcn_mfma_f32_16x16x32_bf16(
              af[m], bfv[n], acc[m][n], 0, 0, 0);
    }
    __syncthreads();
  }

  const int orow0 = row0 + wr * 64;
  const int ocol0 = col0 + wc * 64;
#pragma unroll
  for (int m = 0; m < 4; ++m)
#pragma unroll
    for (int n = 0; n < 4; ++n)
#pragma unroll
      for (int j = 0; j < 4; ++j) {
        int rr = orow0 + m * 16 + (lane >> 4) * 4 + j;
        int cc = ocol0 + n * 16 + (lane & 15);
        if (FP32OUT)
          outf[(size_t)rr * ldc + cc] = acc[m][n][j] + bias[cc];
        else
          outb[(size_t)rr * ldc + cc] =
              __builtin_bit_cast(u16, (__bf16)acc[m][n][j]);
      }
}

// ---------------- causal flash attention (swapped QK^T, paired q-tiles) ----
// Block: 256 thr = 4 waves; block handles TWO 64-row q-tiles of one (b,h):
// qa = blockIdx.x (0..15) and qb = 31-qa, sequentially. Every block does
// exactly (qa+1)+(qb+1) = 33 K-tile visits -> uniform work, zero tail.
// Wave w owns 16 q-rows (lane&15 = qrow). Swapped S^T = mfma(K,Q): each lane
// holds 16 scores of ONE q-row; softmax = in-lane + 2 shfl_xor. exp2-domain,
// T13 exact defer-rescale. Double-buffered K/V, 1 barrier/visit.
__global__ __launch_bounds__(256, 2)
void flash_kernel(const u16* __restrict__ qkv, u16* __restrict__ attn_out) {
  __shared__ __align__(16) u16 sK[2][64 * 64];       // swizzled [kpos][64]
  __shared__ __align__(16) u16 sVt[2][64 * 72];      // [d][kpos] pad 72
  __shared__ __align__(16) u16 sP[4][16][72];        // [wave][qrow][kpos]

  const int tid = threadIdx.x;
  const int lane = tid & 63;
  const int l15 = lane & 15;
  const int hi = lane >> 4;
  const int w = tid >> 6;
  const int bh = blockIdx.y;           // 0..31
  const int b = bh >> 4, h = bh & 15;

  const int NQT = T / 64;              // 32
  const int qa = blockIdx.x;           // 0..15
  const int qb = (NQT - 1) - qa;       // 31..16
  const int na = qa + 1;
  const int nv = na + qb + 1;          // 33 visits

  const size_t base = (size_t)b * T * 3072;
  const u16* qp = qkv + base + 0 * 1024 + h * 64;
  const u16* kp = qkv + base + 1 * 1024 + h * 64;
  const u16* vp = qkv + base + 2 * 1024 + h * 64;

  constexpr float SCALE2 = 0.125f * 1.44269504089f;  // 1/sqrt(64) * log2(e)

  ushort4 vr[2][2];
  auto stageK = [&](u16* dst, int kt) {
#pragma unroll
    for (int i = 0; i < 2; ++i) {
      int off = i * 4096 + tid * 16;
      int r = off >> 7;
      int cs = (off >> 4) & 7;
      int c = cs ^ (r & 7);
      GLD_LDS16(kp + (size_t)(kt * 64 + r) * 3072 + c * 8,
                dst + (i * 4096 + (tid & ~63) * 16) / 2);
    }
  };
  auto loadV = [&](int kt) {
#pragma unroll
    for (int i = 0; i < 2; ++i) {
      const u16* gsrc = vp + (size_t)(kt * 64 + lane) * 3072 + (i * 4 + w) * 8;
      vr[i][0] = ((const ushort4*)gsrc)[0];
      vr[i][1] = ((const ushort4*)gsrc)[1];
    }
  };
  auto writeV = [&](u16* dst) {   // bank = 4k + lane/2 : 2-way (free)
#pragma unroll
    for (int i = 0; i < 2; ++i) {
      int c = i * 4 + w;
      dst[(c * 8 + 0) * 72 + lane] = vr[i][0].x;
      dst[(c * 8 + 1) * 72 + lane] = vr[i][0].y;
      dst[(c * 8 + 2) * 72 + lane] = vr[i][0].z;
      dst[(c * 8 + 3) * 72 + lane] = vr[i][0].w;
      dst[(c * 8 + 4) * 72 + lane] = vr[i][1].x;
      dst[(c * 8 + 5) * 72 + lane] = vr[i][1].y;
      dst[(c * 8 + 6) * 72 + lane] = vr[i][1].z;
      dst[(c * 8 + 7) * 72 + lane] = vr[i][1].w;
    }
  };

  bf16x8 qf[2];
  auto loadQ = [&](int q0) {
#pragma unroll
    for (int kk = 0; kk < 2; ++kk)
      qf[kk] = *(const bf16x8*)(qp + (size_t)(q0 + w * 16 + l15) * 3072 +
                                kk * 32 + hi * 8);
  };

  f32x4 o_acc[4];
  float m2, l_run;
  auto resetAcc = [&]() {
#pragma unroll
    for (int n = 0; n < 4; ++n) o_acc[n] = (f32x4){0.f, 0.f, 0.f, 0.f};
    m2 = -INFINITY;
    l_run = 0.f;
  };
  auto storeO = [&](int q0) {
#pragma unroll
    for (int j = 0; j < 4; ++j) {
      float lj = __shfl(l_run, hi * 4 + j, 64);
      float inv = 1.f / lj;
      int row = q0 + w * 16 + hi * 4 + j;
#pragma unroll
      for (int n = 0; n < 4; ++n) {
        int cc = h * 64 + n * 16 + l15;
        attn_out[((size_t)b * T + row) * 1024 + cc] =
            __builtin_bit_cast(u16, (__bf16)(o_acc[n][j] * inv));
      }
    }
  };

  // prologue: stage K/V tile 0, load Q for pass A
  stageK(sK[0], 0);
  loadV(0);
  writeV(sVt[0]);
  loadQ(qa * 64);
  resetAcc();
  int q0 = qa * 64;
  __syncthreads();

  for (int v = 0; v < nv; ++v) {
    const int cur = v & 1;
    const int kt = (v < na) ? v : v - na;
    const int k0 = kt * 64;
    if (v + 1 < nv) {
      int ktn = (v + 1 < na) ? v + 1 : v + 1 - na;
      stageK(sK[cur ^ 1], ktn);
      loadV(ktn);
    }

    // K fragments (A-operand: row = kpos-within-tile = n*16+l15)
    bf16x8 kf[2][4];
#pragma unroll
    for (int kk = 0; kk < 2; ++kk)
#pragma unroll
      for (int n = 0; n < 4; ++n) {
        int rk = n * 16 + l15;
        int cs = (kk * 4 + hi) ^ (rk & 7);
        kf[kk][n] = *(const bf16x8*)(&sK[cur][rk * 64 + cs * 8]);
      }

    // S^T = K @ Q^T : lane holds S[kpos = n*16+hi*4+r][qrow = l15]
    f32x4 sc[4];
#pragma unroll
    for (int n = 0; n < 4; ++n) sc[n] = (f32x4){0.f, 0.f, 0.f, 0.f};
#pragma unroll
    for (int kk = 0; kk < 2; ++kk)
#pragma unroll
      for (int n = 0; n < 4; ++n)
        sc[n] = __builtin_amdgcn_mfma_f32_16x16x32_bf16(kf[kk][n], qf[kk],
                                                        sc[n], 0, 0, 0);

    // scale to exp2 domain + causal mask (diagonal visits only) + row max
    const bool diag = (v == na - 1) || (v == nv - 1);
    const int qrow = q0 + w * 16 + l15;
    float mx = -INFINITY;
#pragma unroll
    for (int n = 0; n < 4; ++n)
#pragma unroll
      for (int r = 0; r < 4; ++r) {
        float sv = sc[n][r] * SCALE2;
        if (diag) {
          int kpos = k0 + n * 16 + hi * 4 + r;
          if (kpos > qrow) sv = -INFINITY;
        }
        sc[n][r] = sv;
        mx = fmaxf(mx, sv);
      }
    mx = fmaxf(mx, __shfl_xor(mx, 16, 64));
    mx = fmaxf(mx, __shfl_xor(mx, 32, 64));

    // T13: exact defer — skip rescale when no row's max grew
    const bool skip = __all(mx <= m2);
    float alpha = 1.f;
    if (!skip) {
      float mn = fmaxf(m2, mx);
      alpha = EXP2F(m2 - mn);
      m2 = mn;
    }

    float sum = 0.f;
#pragma unroll
    for (int n = 0; n < 4; ++n) {
      float p0 = EXP2F(sc[n][0] - m2);
      float p1 = EXP2F(sc[n][1] - m2);
      float p2 = EXP2F(sc[n][2] - m2);
      float p3 = EXP2F(sc[n][3] - m2);
      sum += (p0 + p1) + (p2 + p3);
      u32 w01 = ((u32)__builtin_bit_cast(u16, (__bf16)p1) << 16) |
                __builtin_bit_cast(u16, (__bf16)p0);
      u32 w23 = ((u32)__builtin_bit_cast(u16, (__bf16)p3) << 16) |
                __builtin_bit_cast(u16, (__bf16)p2);
      *(u32*)(&sP[w][l15][n * 16 + hi * 4 + 0]) = w01;
      *(u32*)(&sP[w][l15][n * 16 + hi * 4 + 2]) = w23;
    }
    sum += __shfl_xor(sum, 16, 64);
    sum += __shfl_xor(sum, 32, 64);
    l_run = l_run * alpha + sum;

    // V fragments (B-operand: col = l15 = d-within-tile, k = kpos)
    bf16x8 vf[2][4];
#pragma unroll
    for (int ks = 0; ks < 2; ++ks)
#pragma unroll
      for (int n = 0; n < 4; ++n)
        vf[ks][n] = *(const bf16x8*)(
            &sVt[cur][(n * 16 + l15) * 72 + ks * 32 + hi * 8]);

    // O rescale (skipped when deferred) + O += P @ V
    if (!skip) {
      float ab[4];
#pragma unroll
      for (int j = 0; j < 4; ++j) ab[j] = __shfl(alpha, hi * 4 + j, 64);
#pragma unroll
      for (int n = 0; n < 4; ++n)
#pragma unroll
        for (int j = 0; j < 4; ++j) o_acc[n][j] *= ab[j];
    }
#pragma unroll
    for (int ks = 0; ks < 2; ++ks) {
      bf16x8 pf = *(const bf16x8*)(&sP[w][l15][ks * 32 + hi * 8]);
#pragma unroll
      for (int n = 0; n < 4; ++n)
        o_acc[n] = __builtin_amdgcn_mfma_f32_16x16x32_bf16(pf, vf[ks][n],
                                                           o_acc[n], 0, 0, 0);
    }

    if (v + 1 < nv) writeV(sVt[cur ^ 1]);

    if (v == na - 1) {                  // pass A done: store, switch to qb
      storeO(q0);
      resetAcc();
      q0 = qb * 64;
      loadQ(q0);
    }
    if (v + 1 < nv) __syncthreads();
  }
  storeO(q0);
}

// ---------------- launch ----------------
extern "C" void kernel_launch(void* const* d_in, const int* in_sizes, int n_in,
                              void* d_out, int out_size, void* d_ws,
                              size_t ws_size, hipStream_t stream) {
  (void)in_sizes; (void)n_in; (void)out_size; (void)ws_size;
  const float* x = (const float*)d_in[0];
  const float* Wqkv = (const float*)d_in[1];
  const float* Wout = (const float*)d_in[2];
  const float* bout = (const float*)d_in[3];
  float* out = (float*)d_out;

  char* ws = (char*)d_ws;
  u16* x_bf = (u16*)(ws + 0);                 //  8388608 B
  u16* wqkv_bf = (u16*)(ws + 8388608);        //  6291456 B
  u16* wout_bf = (u16*)(ws + 14680064);       //  2097152 B
  u16* qkvb = (u16*)(ws + 16777216);          // 25165824 B
  u16* aout = (u16*)(ws + 41943040);          //  8388608 B (end 50331648)

  f32_to_bf16_kernel<<<2048, 256, 0, stream>>>(x, x_bf, M * D / 4);
  f32_to_bf16_kernel<<<2048, 256, 0, stream>>>(Wqkv, wqkv_bf, NQKV * D / 4);
  f32_to_bf16_kernel<<<1024, 256, 0, stream>>>(Wout, wout_bf, D * D / 4);

  gemm_bt<false><<<dim3(NQKV / 128, M / 128), 256, 0, stream>>>(
      x_bf, wqkv_bf, qkvb, nullptr, nullptr, D, NQKV);

  flash_kernel<<<dim3(T / 128, Bz * H), 256, 0, stream>>>(qkvb, aout);

  gemm_bt<true><<<dim3(D / 128, M / 128), 256, 0, stream>>>(
      aout, wout_bf, nullptr, out, bout, D, D);
}

// Round 5
// 113.427 us; speedup vs baseline: 2.0147x; 1.1403x over previous
//
#include <hip/hip_runtime.h>
#include <hip/hip_bf16.h>
#include <math.h>

typedef __bf16 bf16x8 __attribute__((ext_vector_type(8)));
typedef float f32x4 __attribute__((ext_vector_type(4)));
typedef unsigned short u16;
typedef unsigned int u32;

#define EXP2F(x) __builtin_amdgcn_exp2f(x)

// Problem constants
constexpr int Bz = 2, T = 2048, D = 1024, H = 16;
constexpr int M = Bz * T;       // 4096 rows
constexpr int NQKV = 3 * D;     // 3072
constexpr float SCALE2 = 0.125f * 1.44269504089f;  // 1/sqrt(64) * log2(e)

#define GLD_LDS16(g, l) __builtin_amdgcn_global_load_lds( \
    (__attribute__((address_space(1))) void*)(g),          \
    (__attribute__((address_space(3))) void*)(l), 16, 0, 0)

// ---------------- fp32 -> bf16 conversion ----------------
__global__ void f32_to_bf16_kernel(const float* __restrict__ in,
                                   u16* __restrict__ out, int n4) {
  int i = blockIdx.x * blockDim.x + threadIdx.x;
  int stride = gridDim.x * blockDim.x;
  for (; i < n4; i += stride) {
    float4 f = ((const float4*)in)[i];
    ushort4 u;
    u.x = __builtin_bit_cast(u16, (__bf16)f.x);
    u.y = __builtin_bit_cast(u16, (__bf16)f.y);
    u.z = __builtin_bit_cast(u16, (__bf16)f.z);
    u.w = __builtin_bit_cast(u16, (__bf16)f.w);
    ((ushort4*)out)[i] = u;
  }
}

// ---------------- bf16 NT GEMM: C[M,N] = A[M,K] * B[N,K]^T ----------------
// QSCALE: multiply bf16 output by SCALE2 for cols < 1024 (the q-third of qkv)
// so flash's softmax is already in exp2 domain.
template <bool FP32OUT, bool QSCALE>
__global__ __launch_bounds__(256, 2)
void gemm_bt(const u16* __restrict__ A, const u16* __restrict__ Bm,
             u16* __restrict__ outb, float* __restrict__ outf,
             const float* __restrict__ bias, int K, int ldc) {
  __shared__ __align__(16) u16 sA[128 * 64];
  __shared__ __align__(16) u16 sB[128 * 64];
  const int tid = threadIdx.x;
  const int lane = tid & 63;
  const int wid = tid >> 6;
  const int wr = wid >> 1, wc = wid & 1;

  // XCD swizzle (bijective; grids here are %8 == 0)
  const int nwg = gridDim.x * gridDim.y;
  const int flat = blockIdx.y * gridDim.x + blockIdx.x;
  const int cpx = nwg >> 3;
  const int swz = (flat & 7) * cpx + (flat >> 3);
  const int bx = swz % gridDim.x;
  const int by = swz / gridDim.x;

  const int row0 = by * 128;
  const int col0 = bx * 128;

  f32x4 acc[4][4];
#pragma unroll
  for (int m = 0; m < 4; ++m)
#pragma unroll
    for (int n = 0; n < 4; ++n) acc[m][n] = (f32x4){0.f, 0.f, 0.f, 0.f};

  const int nk = K >> 6;
  for (int kt = 0; kt < nk; ++kt) {
    const int k0 = kt << 6;
#pragma unroll
    for (int i = 0; i < 4; ++i) {
      int off = i * 4096 + tid * 16;       // linear byte offset in tile
      int r = off >> 7;                    // row (128B rows)
      int cs = (off >> 4) & 7;             // stored chunk
      int c = cs ^ (r & 7);                // logical (source) chunk
      const u16* ga = A + (size_t)(row0 + r) * K + k0 + c * 8;
      const u16* gb = Bm + (size_t)(col0 + r) * K + k0 + c * 8;
      u16* la = sA + (i * 4096 + (tid & ~63) * 16) / 2;  // wave-uniform base
      u16* lb = sB + (i * 4096 + (tid & ~63) * 16) / 2;
      GLD_LDS16(ga, la);
      GLD_LDS16(gb, lb);
    }
    __syncthreads();
#pragma unroll
    for (int kk = 0; kk < 2; ++kk) {
      bf16x8 af[4], bfv[4];
#pragma unroll
      for (int m = 0; m < 4; ++m) {
        int r = wr * 64 + m * 16 + (lane & 15);
        int cs = (kk * 4 + (lane >> 4)) ^ (r & 7);
        af[m] = *(const bf16x8*)(sA + r * 64 + cs * 8);
      }
#pragma unroll
      for (int n = 0; n < 4; ++n) {
        int r = wc * 64 + n * 16 + (lane & 15);
        int cs = (kk * 4 + (lane >> 4)) ^ (r & 7);
        bfv[n] = *(const bf16x8*)(sB + r * 64 + cs * 8);
      }
#pragma unroll
      for (int m = 0; m < 4; ++m)
#pragma unroll
        for (int n = 0; n < 4; ++n)
          acc[m][n] = __builtin_amdgcn_mfma_f32_16x16x32_bf16(
              af[m], bfv[n], acc[m][n], 0, 0, 0);
    }
    __syncthreads();
  }

  const int orow0 = row0 + wr * 64;
  const int ocol0 = col0 + wc * 64;
#pragma unroll
  for (int m = 0; m < 4; ++m)
#pragma unroll
    for (int n = 0; n < 4; ++n)
#pragma unroll
      for (int j = 0; j < 4; ++j) {
        int rr = orow0 + m * 16 + (lane >> 4) * 4 + j;
        int cc = ocol0 + n * 16 + (lane & 15);
        if (FP32OUT) {
          outf[(size_t)rr * ldc + cc] = acc[m][n][j] + bias[cc];
        } else {
          float v = acc[m][n][j];
          if (QSCALE && cc < D) v *= SCALE2;
          outb[(size_t)rr * ldc + cc] = __builtin_bit_cast(u16, (__bf16)v);
        }
      }
}

// ---------------- causal flash attention (swapped QK^T) ----------------
// Block: 256 thr = 4 waves; ONE 64-row q-tile per block; grid (bh, tiles)
// with qt = 31 - blockIdx.y so heavy blocks dispatch first. 44KB LDS ->
// 3 blocks/CU co-resident irons out causal imbalance.
// Wave w owns 16 q-rows (lane&15 = qrow). Swapped S^T = mfma(K,Q): each lane
// holds 16 scores of ONE q-row; softmax = in-lane + 2 shfl_xor. Q pre-scaled
// (exp2 domain) by GEMM1. T13 exact defer-rescale. Double-buffered K/V,
// 1 barrier/visit.
__global__ __launch_bounds__(256, 3)
void flash_kernel(const u16* __restrict__ qkv, u16* __restrict__ attn_out) {
  __shared__ __align__(16) u16 sK[2][64 * 64];       // swizzled [kpos][64]
  __shared__ __align__(16) u16 sVt[2][64 * 72];      // [d][kpos] pad 72
  __shared__ __align__(16) u16 sP[4][16][72];        // [wave][qrow][kpos]

  const int tid = threadIdx.x;
  const int lane = tid & 63;
  const int l15 = lane & 15;
  const int hi = lane >> 4;
  const int w = tid >> 6;
  const int bh = blockIdx.x;           // 0..31
  const int b = bh >> 4, h = bh & 15;
  const int qt = (gridDim.y - 1) - blockIdx.y;   // heavy first
  const int q0 = qt * 64;
  const int nv = qt + 1;

  const size_t base = (size_t)b * T * 3072;
  const u16* qp = qkv + base + 0 * 1024 + h * 64;
  const u16* kp = qkv + base + 1 * 1024 + h * 64;
  const u16* vp = qkv + base + 2 * 1024 + h * 64;

  ushort4 vr[2][2];
  auto stageK = [&](u16* dst, int kt) {
#pragma unroll
    for (int i = 0; i < 2; ++i) {
      int off = i * 4096 + tid * 16;
      int r = off >> 7;
      int cs = (off >> 4) & 7;
      int c = cs ^ (r & 7);
      GLD_LDS16(kp + (size_t)(kt * 64 + r) * 3072 + c * 8,
                dst + (i * 4096 + (tid & ~63) * 16) / 2);
    }
  };
  auto loadV = [&](int kt) {
#pragma unroll
    for (int i = 0; i < 2; ++i) {
      const u16* gsrc = vp + (size_t)(kt * 64 + lane) * 3072 + (i * 4 + w) * 8;
      vr[i][0] = ((const ushort4*)gsrc)[0];
      vr[i][1] = ((const ushort4*)gsrc)[1];
    }
  };
  auto writeV = [&](u16* dst) {   // bank = 4k + lane/2 : 2-way (free)
#pragma unroll
    for (int i = 0; i < 2; ++i) {
      int c = i * 4 + w;
      dst[(c * 8 + 0) * 72 + lane] = vr[i][0].x;
      dst[(c * 8 + 1) * 72 + lane] = vr[i][0].y;
      dst[(c * 8 + 2) * 72 + lane] = vr[i][0].z;
      dst[(c * 8 + 3) * 72 + lane] = vr[i][0].w;
      dst[(c * 8 + 4) * 72 + lane] = vr[i][1].x;
      dst[(c * 8 + 5) * 72 + lane] = vr[i][1].y;
      dst[(c * 8 + 6) * 72 + lane] = vr[i][1].z;
      dst[(c * 8 + 7) * 72 + lane] = vr[i][1].w;
    }
  };

  // Q fragments (B-operand layout: col=lane&15=qrow, k=(lane>>4)*8+j)
  bf16x8 qf[2];
#pragma unroll
  for (int kk = 0; kk < 2; ++kk)
    qf[kk] = *(const bf16x8*)(qp + (size_t)(q0 + w * 16 + l15) * 3072 +
                              kk * 32 + hi * 8);

  f32x4 o_acc[4];
#pragma unroll
  for (int n = 0; n < 4; ++n) o_acc[n] = (f32x4){0.f, 0.f, 0.f, 0.f};
  float m2 = -INFINITY, l_run = 0.f;

  // prologue: stage K/V tile 0
  stageK(sK[0], 0);
  loadV(0);
  writeV(sVt[0]);
  __syncthreads();

  for (int v = 0; v < nv; ++v) {
    const int cur = v & 1;
    const int k0 = v * 64;
    if (v + 1 < nv) {
      stageK(sK[cur ^ 1], v + 1);
      loadV(v + 1);
    }

    // K fragments (A-operand: row = kpos-within-tile = n*16+l15)
    bf16x8 kf[2][4];
#pragma unroll
    for (int kk = 0; kk < 2; ++kk)
#pragma unroll
      for (int n = 0; n < 4; ++n) {
        int rk = n * 16 + l15;
        int cs = (kk * 4 + hi) ^ (rk & 7);
        kf[kk][n] = *(const bf16x8*)(&sK[cur][rk * 64 + cs * 8]);
      }

    // S^T = K @ Q^T : lane holds S[kpos = n*16+hi*4+r][qrow = l15]
    f32x4 sc[4];
#pragma unroll
    for (int n = 0; n < 4; ++n) sc[n] = (f32x4){0.f, 0.f, 0.f, 0.f};
#pragma unroll
    for (int kk = 0; kk < 2; ++kk)
#pragma unroll
      for (int n = 0; n < 4; ++n)
        sc[n] = __builtin_amdgcn_mfma_f32_16x16x32_bf16(kf[kk][n], qf[kk],
                                                        sc[n], 0, 0, 0);

    // causal mask (diagonal visit only) + row max (scores already exp2-domain)
    const bool diag = (v == nv - 1);
    const int qrow = q0 + w * 16 + l15;
    float mx = -INFINITY;
#pragma unroll
    for (int n = 0; n < 4; ++n)
#pragma unroll
      for (int r = 0; r < 4; ++r) {
        float sv = sc[n][r];
        if (diag) {
          int kpos = k0 + n * 16 + hi * 4 + r;
          if (kpos > qrow) sv = -INFINITY;
        }
        sc[n][r] = sv;
        mx = fmaxf(mx, sv);
      }
    mx = fmaxf(mx, __shfl_xor(mx, 16, 64));
    mx = fmaxf(mx, __shfl_xor(mx, 32, 64));

    // T13: exact defer — skip rescale when no row's max grew
    const bool skip = __all(mx <= m2);
    float alpha = 1.f;
    if (!skip) {
      float mn = fmaxf(m2, mx);
      alpha = EXP2F(m2 - mn);
      m2 = mn;
    }

    float sum = 0.f;
#pragma unroll
    for (int n = 0; n < 4; ++n) {
      float p0 = EXP2F(sc[n][0] - m2);
      float p1 = EXP2F(sc[n][1] - m2);
      float p2 = EXP2F(sc[n][2] - m2);
      float p3 = EXP2F(sc[n][3] - m2);
      sum += (p0 + p1) + (p2 + p3);
      u32 w01 = ((u32)__builtin_bit_cast(u16, (__bf16)p1) << 16) |
                __builtin_bit_cast(u16, (__bf16)p0);
      u32 w23 = ((u32)__builtin_bit_cast(u16, (__bf16)p3) << 16) |
                __builtin_bit_cast(u16, (__bf16)p2);
      *(u32*)(&sP[w][l15][n * 16 + hi * 4 + 0]) = w01;
      *(u32*)(&sP[w][l15][n * 16 + hi * 4 + 2]) = w23;
    }
    sum += __shfl_xor(sum, 16, 64);
    sum += __shfl_xor(sum, 32, 64);
    l_run = l_run * alpha + sum;

    // V fragments (B-operand: col = l15 = d-within-tile, k = kpos)
    bf16x8 vf[2][4];
#pragma unroll
    for (int ks = 0; ks < 2; ++ks)
#pragma unroll
      for (int n = 0; n < 4; ++n)
        vf[ks][n] = *(const bf16x8*)(
            &sVt[cur][(n * 16 + l15) * 72 + ks * 32 + hi * 8]);

    // O rescale (skipped when deferred) + O += P @ V
    if (!skip) {
      float ab[4];
#pragma unroll
      for (int j = 0; j < 4; ++j) ab[j] = __shfl(alpha, hi * 4 + j, 64);
#pragma unroll
      for (int n = 0; n < 4; ++n)
#pragma unroll
        for (int j = 0; j < 4; ++j) o_acc[n][j] *= ab[j];
    }
#pragma unroll
    for (int ks = 0; ks < 2; ++ks) {
      bf16x8 pf = *(const bf16x8*)(&sP[w][l15][ks * 32 + hi * 8]);
#pragma unroll
      for (int n = 0; n < 4; ++n)
        o_acc[n] = __builtin_amdgcn_mfma_f32_16x16x32_bf16(pf, vf[ks][n],
                                                           o_acc[n], 0, 0, 0);
    }

    if (v + 1 < nv) {
      writeV(sVt[cur ^ 1]);
      __syncthreads();
    }
  }

  // normalize + store bf16 [M][1024]
#pragma unroll
  for (int j = 0; j < 4; ++j) {
    float lj = __shfl(l_run, hi * 4 + j, 64);
    float inv = 1.f / lj;
    int row = q0 + w * 16 + hi * 4 + j;
#pragma unroll
    for (int n = 0; n < 4; ++n) {
      int cc = h * 64 + n * 16 + l15;
      attn_out[((size_t)b * T + row) * 1024 + cc] =
          __builtin_bit_cast(u16, (__bf16)(o_acc[n][j] * inv));
    }
  }
}

// ---------------- launch ----------------
extern "C" void kernel_launch(void* const* d_in, const int* in_sizes, int n_in,
                              void* d_out, int out_size, void* d_ws,
                              size_t ws_size, hipStream_t stream) {
  (void)in_sizes; (void)n_in; (void)out_size; (void)ws_size;
  const float* x = (const float*)d_in[0];
  const float* Wqkv = (const float*)d_in[1];
  const float* Wout = (const float*)d_in[2];
  const float* bout = (const float*)d_in[3];
  float* out = (float*)d_out;

  char* ws = (char*)d_ws;
  u16* x_bf = (u16*)(ws + 0);                 //  8388608 B
  u16* wqkv_bf = (u16*)(ws + 8388608);        //  6291456 B
  u16* wout_bf = (u16*)(ws + 14680064);       //  2097152 B
  u16* qkvb = (u16*)(ws + 16777216);          // 25165824 B
  u16* aout = (u16*)(ws + 41943040);          //  8388608 B (end 50331648)

  f32_to_bf16_kernel<<<2048, 256, 0, stream>>>(x, x_bf, M * D / 4);
  f32_to_bf16_kernel<<<2048, 256, 0, stream>>>(Wqkv, wqkv_bf, NQKV * D / 4);
  f32_to_bf16_kernel<<<1024, 256, 0, stream>>>(Wout, wout_bf, D * D / 4);

  gemm_bt<false, true><<<dim3(NQKV / 128, M / 128), 256, 0, stream>>>(
      x_bf, wqkv_bf, qkvb, nullptr, nullptr, D, NQKV);

  flash_kernel<<<dim3(Bz * H, T / 64), 256, 0, stream>>>(qkvb, aout);

  gemm_bt<true, false><<<dim3(D / 128, M / 128), 256, 0, stream>>>(
      aout, wout_bf, nullptr, out, bout, D, D);
}